// Round 17
// baseline (105.049 us; speedup 1.0000x reference)
//
#include <hip/hip_runtime.h>
#include <stdint.h>

#define SCALE 0.125f   // 1/sqrt(64)
#define GSL_C 0.180336880111f   // SCALE * log2(e)

typedef short s16x4 __attribute__((ext_vector_type(4)));
typedef short s16x8 __attribute__((ext_vector_type(8)));
typedef float f32x4 __attribute__((ext_vector_type(4)));
typedef float f32x16 __attribute__((ext_vector_type(16)));

__device__ __forceinline__ unsigned short f2bf(float x){
  union { float f; unsigned int u; } v; v.f = x;
  unsigned int r = v.u + 0x7fffu + ((v.u >> 16) & 1u);
  return (unsigned short)(r >> 16);
}
__device__ __forceinline__ float bf2f(unsigned short u){
  union { unsigned int u; float f; } v; v.u = ((unsigned int)u) << 16;
  return v.f;
}
__device__ __forceinline__ f32x4 mfma16(s16x8 a, s16x8 b, f32x4 c){
  return __builtin_amdgcn_mfma_f32_16x16x32_bf16(a, b, c, 0, 0, 0);
}
__device__ __forceinline__ f32x16 mfma32(s16x8 a, s16x8 b, f32x16 c){
  return __builtin_amdgcn_mfma_f32_32x32x16_bf16(a, b, c, 0, 0, 0);
}
__device__ __forceinline__ void gld_lds16(const void* g, void* l){
  __builtin_amdgcn_global_load_lds(
      (const __attribute__((address_space(1))) unsigned int*)g,
      (__attribute__((address_space(3))) unsigned int*)l, 16, 0, 0);
}
__device__ __forceinline__ unsigned int cvtpk(float lo, float hi){
  unsigned int r;
  asm("v_cvt_pk_bf16_f32 %0, %1, %2" : "=v"(r) : "v"(lo), "v"(hi));
  return r;
}
__device__ __forceinline__ void plswap(unsigned int &a, unsigned int &b){
  asm("v_permlane32_swap_b32 %0, %1" : "+v"(a), "+v"(b));
}

// ---------------- prep: cast q -> bf16 (bid<2048) + W transpose (bid>=2048) ---
__global__ __launch_bounds__(256) void prep_kernel(const float* __restrict__ in,
    unsigned short* __restrict__ out,
    const float* __restrict__ W0, const float* __restrict__ W1,
    const float* __restrict__ W2, const float* __restrict__ W3,
    unsigned short* __restrict__ Wt){
  int bid = blockIdx.x;
  int tid = threadIdx.x;
  if (bid < 2048){
    int i = bid*256 + tid;
    const float4* p = (const float4*)in + (size_t)i*2;
    float4 a = p[0], b = p[1];
    unsigned short t[8] = {f2bf(a.x),f2bf(a.y),f2bf(a.z),f2bf(a.w),
                           f2bf(b.x),f2bf(b.y),f2bf(b.z),f2bf(b.w)};
    *(s16x8*)(out + (size_t)i*8) = *(const s16x8*)t;
  } else {
    int idx = bid - 2048;
    int z = idx >> 8, rem = idx & 255;
    int k0 = (rem & 15)*64, n0 = (rem >> 4)*64;
    const float* src = (z==0)?W0:(z==1)?W1:(z==2)?W2:W3;
    unsigned short* dst = Wt + (size_t)z*1048576;
    __shared__ unsigned short tile[64*72];
    int r = tid>>2, c = (tid&3)*16;
    const float* p = src + (size_t)(k0+r)*1024 + n0 + c;
    #pragma unroll
    for (int j=0;j<16;j++) tile[r*72 + c + j] = f2bf(p[j]);
    __syncthreads();
    int n = tid>>2, kc = (tid&3)*16;
    unsigned short o[16];
    #pragma unroll
    for (int j=0;j<16;j++) o[j] = tile[(kc+j)*72 + n];
    *(s16x8*)&dst[(size_t)(n0+n)*1024 + k0 + kc]     = *(const s16x8*)o;
    *(s16x8*)&dst[(size_t)(n0+n)*1024 + k0 + kc + 8] = *(const s16x8*)(o+8);
  }
}

// ---------------- 128x128xBK32 bf16 GEMM (projections), dbuf, 32 KB LDS -------
// z<2 -> Qh/Kh heads layout + fused PRESCALED norms; z==2 -> Vt DIRECT
// (transposed via per-wave LDS tile reusing As/Bs after the main loop;
//  bitwise-identical values to the old Vh+vtrans path).
__global__ __launch_bounds__(512) void gemm_proj(const unsigned short* __restrict__ A,
    const unsigned short* __restrict__ Bt, unsigned short* __restrict__ outH,
    unsigned short* __restrict__ VtG,
    float* __restrict__ qn, float* __restrict__ kn, const float* __restrict__ gamma){
  __shared__ short As[2][4096];   // [128][32] per buffer
  __shared__ short Bs[2][4096];
  int tid = threadIdx.x;
  int w = tid>>6, l = tid&63;
  int lm = l & 15, hi = l >> 4;
  int wr = w>>1, wc = w&1;
  int m0 = blockIdx.x*128, n0 = blockIdx.y*128;

  const unsigned short* Bz = Bt + (size_t)(n0>>10)*1048576;
  int bn0 = n0 & 1023;

  f32x4 acc[2][4];
  #pragma unroll
  for (int r=0;r<2;r++)
    #pragma unroll
    for (int c=0;c<4;c++){ f32x4 z = {0.f,0.f,0.f,0.f}; acc[r][c] = z; }

  int srow = w*16 + (l>>2);
  int schk = ((l&3) ^ ((l>>3)&3))*8;
  const unsigned short* gA = A  + (size_t)(m0  + srow)*1024 + schk;
  const unsigned short* gB = Bz + (size_t)(bn0 + srow)*1024 + schk;

  int ch = (hi ^ ((lm>>1)&3))*8;

  gld_lds16(gA, &As[0][w*512]);
  gld_lds16(gB, &Bs[0][w*512]);
  __syncthreads();

  const int NKT = 32;
  int buf = 0;
  for (int kt=0; kt<NKT; ++kt){
    if (kt+1 < NKT){
      gld_lds16(gA + (size_t)(kt+1)*32, &As[buf^1][w*512]);
      gld_lds16(gB + (size_t)(kt+1)*32, &Bs[buf^1][w*512]);
    }
    const short* cA = &As[buf][0];
    const short* cB = &Bs[buf][0];
    s16x8 af[2], bfv[4];
    #pragma unroll
    for (int r=0;r<2;r++)
      af[r]  = *(const s16x8*)(cA + (wr*32 + r*16 + lm)*32 + ch);
    #pragma unroll
    for (int c=0;c<4;c++)
      bfv[c] = *(const s16x8*)(cB + (wc*64 + c*16 + lm)*32 + ch);
    __builtin_amdgcn_s_setprio(1);
    #pragma unroll
    for (int r=0;r<2;r++)
      #pragma unroll
      for (int c=0;c<4;c++)
        acc[r][c] = mfma16(af[r], bfv[c], acc[r][c]);
    __builtin_amdgcn_s_setprio(0);
    __syncthreads();
    buf ^= 1;
  }

  int z = n0 >> 10;
  if (z == 2){
    // --- V path: transpose 32t x 64d per wave through its private LDS tile ---
    short* tb = (w < 4) ? (&As[0][0] + w*2048) : (&Bs[0][0] + (w-4)*2048);
    #pragma unroll
    for (int r=0;r<2;r++)
      #pragma unroll
      for (int c=0;c<4;c++){
        unsigned short t4[4] = {f2bf(acc[r][c][0]), f2bf(acc[r][c][1]),
                                f2bf(acc[r][c][2]), f2bf(acc[r][c][3])};
        // tile[d][tl]: d = c*16+lm (0..63), tl = r*16 + hi*4 (4 consecutive t)
        *(s16x4*)(tb + (c*16 + lm)*32 + r*16 + hi*4) = *(const s16x4*)t4;
      }
    // wave reads only its own tile: lgkmcnt ordering suffices, no barrier
    int bq = m0 >> 11;
    int hq = (bn0 >> 6) + wc;
    int bh = bq*16 + hq;
    int t0w = (m0 & 2047) + wr*32;
    unsigned short* vt = VtG + (size_t)bh*131072;
    #pragma unroll
    for (int it=0; it<4; ++it){
      int d = (l>>2) + it*16;
      int tl = (l&3)*8;
      s16x8 vv = *(const s16x8*)(tb + d*32 + tl);
      *(s16x8*)(vt + (size_t)d*2048 + t0w + tl) = vv;
    }
  } else {
    unsigned short* oz = outH + (size_t)z*4194304;
    #pragma unroll
    for (int r=0;r<2;r++){
      #pragma unroll
      for (int i=0;i<4;i++){
        int m = m0 + wr*32 + r*16 + hi*4 + i;
        int bq = m >> 11, sq = m & 2047;
        float nrm = 0.f;
        #pragma unroll
        for (int c=0;c<4;c++){
          int nn = bn0 + wc*64 + c*16 + lm;
          int hq = nn >> 6, dq = nn & 63;
          int bh = bq*16 + hq;
          unsigned short bv = f2bf(acc[r][c][i]);
          oz[((size_t)bh*2048 + sq)*64 + dq] = bv;
          float vf = bf2f(bv);
          nrm = fmaf(vf, vf, nrm);
        }
        nrm += __shfl_xor(nrm, 1);
        nrm += __shfl_xor(nrm, 2);
        nrm += __shfl_xor(nrm, 4);
        nrm += __shfl_xor(nrm, 8);
        if (lm == 0){
          int hq = (bn0 + wc*64) >> 6;
          float gsl_h = gamma[hq] * GSL_C;
          float* dst = z ? kn : qn;
          dst[(size_t)(bq*16 + hq)*2048 + sq] = nrm * gsl_h;
        }
      }
    }
  }
}

// ---------------- Wo GEMM 128x64xBK64, dbuf, grid 512 (2 blocks/CU) ----------
__global__ __launch_bounds__(512) void gemm_out(const unsigned short* __restrict__ A,
    const unsigned short* __restrict__ Bt, float* __restrict__ outF){
  __shared__ short As[16384];   // 2 x [128][64]
  __shared__ short Bs[8192];    // 2 x [64][64]
  int tid = threadIdx.x;
  int w = tid>>6, l = tid&63;
  int lm = l & 15, hi = l >> 4;
  int wr = w>>1, wc = w&1;
  int m0 = blockIdx.x*128, n0 = blockIdx.y*64;

  f32x4 acc[2][2];
  #pragma unroll
  for (int r=0;r<2;r++)
    #pragma unroll
    for (int c=0;c<2;c++){ f32x4 z = {0.f,0.f,0.f,0.f}; acc[r][c] = z; }

  int rsub = l>>3, csw = ((l&7) ^ (l>>3))*8;
  const unsigned short* gA = A  + (size_t)(m0 + w*16 + rsub)*1024 + csw;
  const unsigned short* gB = Bt + (size_t)(n0 + w*8  + rsub)*1024 + csw;

  int ch0 = ((hi)     ^ (lm&7))*8;
  int ch1 = ((4 + hi) ^ (lm&7))*8;

  gld_lds16(gA,        As + w*1024);
  gld_lds16(gA + 8192, As + w*1024 + 512);
  gld_lds16(gB,        Bs + w*512);
  __syncthreads();

  const int NKT = 16;
  int buf = 0;
  for (int kt=0; kt<NKT; ++kt){
    if (kt+1 < NKT){
      const unsigned short* a = gA + (size_t)(kt+1)*64;
      const unsigned short* b = gB + (size_t)(kt+1)*64;
      gld_lds16(a,        As + (buf^1)*8192 + w*1024);
      gld_lds16(a + 8192, As + (buf^1)*8192 + w*1024 + 512);
      gld_lds16(b,        Bs + (buf^1)*4096 + w*512);
    }
    const short* curA = As + buf*8192;
    const short* curB = Bs + buf*4096;
    s16x8 af[2][2], bfv[2][2];
    #pragma unroll
    for (int r=0;r<2;r++){
      int ro = (wr*32 + r*16 + lm)*64;
      af[r][0] = *(const s16x8*)(curA + ro + ch0);
      af[r][1] = *(const s16x8*)(curA + ro + ch1);
    }
    #pragma unroll
    for (int c=0;c<2;c++){
      int ro = (wc*32 + c*16 + lm)*64;
      bfv[c][0] = *(const s16x8*)(curB + ro + ch0);
      bfv[c][1] = *(const s16x8*)(curB + ro + ch1);
    }
    __builtin_amdgcn_s_setprio(1);
    #pragma unroll
    for (int s=0;s<2;s++)
      #pragma unroll
      for (int r=0;r<2;r++)
        #pragma unroll
        for (int c=0;c<2;c++)
          acc[r][c] = mfma16(af[r][s], bfv[c][s], acc[r][c]);
    __builtin_amdgcn_s_setprio(0);
    __syncthreads();
    buf ^= 1;
  }

  #pragma unroll
  for (int r=0;r<2;r++)
    #pragma unroll
    for (int c=0;c<2;c++)
      #pragma unroll
      for (int i=0;i<4;i++){
        int m = m0 + wr*32 + r*16 + hi*4 + i;
        int n = n0 + wc*32 + c*16 + lm;
        outF[(size_t)m*1024 + n] = acc[r][c][i];
      }
}

// ---------------- attention (32x32 MFMA, in-reg P, tb-interleaved ILP) --------
#define JOB(si,ts,te,buf,zm) ((unsigned int)((si)|((ts)<<4)|((te)<<10)|((buf)<<16)|((zm)<<18)))
__device__ const unsigned int JOBS[32] = {
  JOB(0,0,11,0,0),   JOB(5,10,21,0,0),  JOB(0,22,32,2,0),  JOB(1,12,22,1,0),
  JOB(2,4,14,0,0),   JOB(6,22,32,1,2),  JOB(2,23,32,2,0),  JOB(7,14,23,0,0),
  JOB(0,11,22,1,0),  JOB(5,21,32,1,2),  JOB(1,2,12,0,0),   JOB(1,22,32,2,0),
  JOB(6,12,22,0,0),  JOB(2,14,23,1,0),  JOB(3,6,15,0,0),   JOB(7,23,32,1,2),
  JOB(11,22,32,0,3), JOB(3,24,32,2,0),  JOB(4,8,16,0,0),   JOB(4,16,24,1,0),
  JOB(4,24,32,2,0),  JOB(8,16,24,0,0),  JOB(3,15,24,1,0),  JOB(8,24,32,1,2),
  JOB(15,30,32,0,3), JOB(14,28,32,0,3), JOB(10,20,26,0,0), JOB(10,26,32,1,2),
  JOB(13,26,32,0,3), JOB(9,18,25,0,0),  JOB(9,25,32,1,2),  JOB(12,24,32,0,3)
};

__global__ __launch_bounds__(256, 4) void attn_kernel(const unsigned short* __restrict__ Qh,
    const unsigned short* __restrict__ Kh, const unsigned short* __restrict__ VtG,
    const float* __restrict__ qn, const float* __restrict__ kn,
    const float* __restrict__ gamma, unsigned short* __restrict__ aO0,
    unsigned short* __restrict__ aO1, unsigned short* __restrict__ aO2){
  __shared__ short Ks[2][4096];   // [t 64][d 64], chunk-swizzled
  __shared__ short Vs[2][4096];   // [d 64][t 64], chunk-swizzled

  int bid = blockIdx.x;
  int bh = bid & 31; int b = bh>>4, h = bh&15;
  unsigned int e = JOBS[bid >> 5];
  int si2 = e & 15, ts = (e>>4)&63, te = (e>>10)&63, bsel = (e>>16)&3, zm = (e>>18)&3;
  int s0 = si2*128;

  int tid = threadIdx.x, w = tid>>6, l = tid&63;
  int l31 = l & 31, hi5 = l >> 5, l7 = l & 7;
  float gs2l = 2.f * gamma[h] * GSL_C;

  int q0 = s0 + w*32;            // wave's 32 q-rows
  int qrow = q0 + l31;
  const unsigned short* qb = Qh + ((size_t)bh*2048 + qrow)*64;
  s16x8 qf[4];
  #pragma unroll
  for (int c=0;c<4;c++) qf[c] = *(const s16x8*)(qb + c*16 + hi5*8);
  float gq = -qn[(size_t)bh*2048 + qrow];   // prescaled
  const float* knp = kn + (size_t)bh*2048;

  int chs = (l7 ^ (l>>3))*8;
  const unsigned short* kp0 = Kh  + ((size_t)bh*2048 + w*8 + (l>>3))*64 + chs;
  const unsigned short* vp0 = VtG + ((size_t)bh*64 + w*8 + (l>>3))*2048 + chs;

  f32x16 accO0, accO1;
  #pragma unroll
  for (int r=0;r<16;r++){ accO0[r] = 0.f; accO1[r] = 0.f; }

#define STAGE(bufi, tabs) { \
    const unsigned short* kp = kp0 + (size_t)(tabs)*64; \
    const unsigned short* vp = vp0 + (tabs); \
    short* dK = &Ks[bufi][w*512]; \
    short* dV = &Vs[bufi][w*512]; \
    gld_lds16(kp,           dK); \
    gld_lds16(kp + 32*64,   dK + 2048); \
    gld_lds16(vp,           dV); \
    gld_lds16(vp + 32*2048, dV + 2048); \
  }

  STAGE(0, ts*64);
  __syncthreads();

  int cur = 0;
  for (int tt = ts; tt < te; ++tt, cur ^= 1){
    int t0 = tt*64;
    if (tt + 1 < te) STAGE(cur^1, (tt+1)*64);
    const short* kb = &Ks[cur][0];
    const short* vb = &Vs[cur][0];

    // ---- phase 1: QK for both 32-blocks ----
    f32x16 sc2[2];
    #pragma unroll
    for (int tb=0; tb<2; tb++){
      int tbase = t0 + tb*32 - s0;
      if (tbase + 31 <= w*32) continue;     // fully masked: skip
      f32x16 sc;
      #pragma unroll
      for (int r=0;r<16;r++) sc[r] = 0.f;
      __builtin_amdgcn_s_setprio(1);
      #pragma unroll
      for (int c=0;c<4;c++){
        s16x8 kf = *(const s16x8*)(kb + (tb*32 + l31)*64 + (((2*c + hi5) ^ l7)*8));
        sc = mfma32(kf, qf[c], sc);
      }
      __builtin_amdgcn_s_setprio(0);
      sc2[tb] = sc;
    }

    // ---- phase 2: transform + PV per block ----
    #pragma unroll
    for (int tb=0; tb<2; tb++){
      int tbase = t0 + tb*32 - s0;
      if (tbase + 31 <= w*32) continue;
      f32x16 sc = sc2[tb];
      float ev[16];
      #pragma unroll
      for (int gg=0; gg<4; gg++){
        float4 knv = *(const float4*)(knp + t0 + tb*32 + gg*8 + hi5*4);
        float ks4[4] = {knv.x, knv.y, knv.z, knv.w};
        #pragma unroll
        for (int i=0;i<4;i++){
          int r = gg*4 + i;
          ev[r] = __builtin_amdgcn_exp2f(fminf(fmaf(gs2l, sc[r], gq - ks4[i]), 0.f));
        }
      }
      if (tbase < w*32 + 32){               // partial mask (strict upper: keep t>q)
        #pragma unroll
        for (int r=0;r<16;r++){
          int t = t0 + tb*32 + (r&3) + 8*(r>>2) + 4*hi5;
          ev[r] = (t > qrow) ? ev[r] : 0.f;
        }
      }
      unsigned int u0 = cvtpk(ev[0],  ev[1]),  u1 = cvtpk(ev[2],  ev[3]);
      unsigned int u2 = cvtpk(ev[4],  ev[5]),  u3 = cvtpk(ev[6],  ev[7]);
      unsigned int u4 = cvtpk(ev[8],  ev[9]),  u5 = cvtpk(ev[10], ev[11]);
      unsigned int u6 = cvtpk(ev[12], ev[13]), u7 = cvtpk(ev[14], ev[15]);
      plswap(u0, u2);
      plswap(u1, u3);
      plswap(u4, u6);
      plswap(u5, u7);
      unsigned int f0[4] = {u0, u1, u2, u3};
      unsigned int f1[4] = {u4, u5, u6, u7};
      s16x8 pa0 = *(const s16x8*)f0;
      s16x8 pa1 = *(const s16x8*)f1;
      __builtin_amdgcn_s_setprio(1);
      {
        int cg0 = 2*tb, cg1 = 2*tb + 1;
        s16x8 v00 = *(const s16x8*)(vb + (l31)*64      + (((2*cg0 + hi5) ^ l7)*8));
        s16x8 v01 = *(const s16x8*)(vb + (l31)*64      + (((2*cg1 + hi5) ^ l7)*8));
        s16x8 v10 = *(const s16x8*)(vb + (32 + l31)*64 + (((2*cg0 + hi5) ^ l7)*8));
        s16x8 v11 = *(const s16x8*)(vb + (32 + l31)*64 + (((2*cg1 + hi5) ^ l7)*8));
        accO0 = mfma32(pa0, v00, accO0);
        accO0 = mfma32(pa1, v01, accO0);
        accO1 = mfma32(pa0, v10, accO1);
        accO1 = mfma32(pa1, v11, accO1);
      }
      __builtin_amdgcn_s_setprio(0);
    }
    __syncthreads();
  }
#undef STAGE

  unsigned short* aoP = (bsel==0) ? aO0 : (bsel==1) ? aO1 : aO2;
  #pragma unroll
  for (int r=0;r<16;r++){
    int s = q0 + (r&3) + 8*(r>>2) + 4*hi5;
    size_t base = ((size_t)b*2048 + s)*1024 + h*64;
    aoP[base + l31]      = f2bf(accO0[r]);
    aoP[base + 32 + l31] = f2bf(accO1[r]);
  }
  if (zm){
    s16x8 zz8 = {0,0,0,0,0,0,0,0};
    int zr = tid >> 1, zc = (tid & 1)*32;
    size_t zbase = ((size_t)b*2048 + s0 + zr)*1024 + h*64 + zc;
    if (zm & 1){
      #pragma unroll
      for (int j=0;j<4;j++) *(s16x8*)&aO1[zbase + j*8] = zz8;
    }
    if (zm & 2){
      #pragma unroll
      for (int j=0;j<4;j++) *(s16x8*)&aO2[zbase + j*8] = zz8;
    }
  }
}

// ---------------- sum of 3 bf16 partial buffers -> aO0 ----------------
__global__ __launch_bounds__(256) void sum3_kernel(unsigned short* __restrict__ a,
    const unsigned short* __restrict__ bsrc, const unsigned short* __restrict__ csrc){
  size_t i = ((size_t)blockIdx.x*256 + threadIdx.x)*8;
  s16x8 va = *(const s16x8*)(a + i);
  s16x8 vb = *(const s16x8*)(bsrc + i);
  s16x8 vc = *(const s16x8*)(csrc + i);
  unsigned short o[8];
  #pragma unroll
  for (int j=0;j<8;j++)
    o[j] = f2bf(bf2f((unsigned short)va[j]) + bf2f((unsigned short)vb[j])
                + bf2f((unsigned short)vc[j]));
  *(s16x8*)(a + i) = *(const s16x8*)o;
}

extern "C" void kernel_launch(void* const* d_in, const int* in_sizes, int n_in,
                              void* d_out, int out_size, void* d_ws, size_t ws_size,
                              hipStream_t stream){
  const float* q  = (const float*)d_in[0];
  const float* Wq = (const float*)d_in[1];
  const float* Wk = (const float*)d_in[2];
  const float* Wv = (const float*)d_in[3];
  const float* Wo = (const float*)d_in[4];
  const float* gm = (const float*)d_in[5];
  float* out = (float*)d_out;

  unsigned short* qbf = (unsigned short*)d_ws;  // dead after gemm_proj -> aO1
  unsigned short* Wt  = qbf + 4194304;          // 4 x [1024][1024] bf16 (B^T form)
  unsigned short* Qh  = Wt  + 4194304;          // [bh][2048][64]
  unsigned short* Kh  = Qh  + 4194304;
  unsigned short* Vh  = Kh  + 4194304;          // now purely aO2 (partial buffer)
  unsigned short* Vt  = Vh  + 4194304;          // [bh][64][2048], written by gemm_proj
  unsigned short* aO  = Vt  + 4194304;          // partial 0 + final sum
  float* qn = (float*)(aO + 4194304);           // [bh*2048], prescaled
  float* kn = qn + 65536;

  unsigned short* aO1 = qbf;
  unsigned short* aO2 = Vh;

  prep_kernel  <<<dim3(3072), 256, 0, stream>>>(q, qbf, Wq, Wk, Wv, Wo, Wt);
  gemm_proj    <<<dim3(32,24), 512, 0, stream>>>(qbf, Wt, Qh, Vt, qn, kn, gm);
  attn_kernel  <<<dim3(1024), 256, 0, stream>>>(Qh, Kh, Vt, qn, kn, gm, aO, aO1, aO2);
  sum3_kernel  <<<dim3(2048), 256, 0, stream>>>(aO, aO1, aO2);
  gemm_out     <<<dim3(32,16), 512, 0, stream>>>(aO, Wt + 3*1048576, out);
}

// Round 18
// 100.605 us; speedup vs baseline: 1.0442x; 1.0442x over previous
//
#include <hip/hip_runtime.h>
#include <stdint.h>

#define SCALE 0.125f   // 1/sqrt(64)
#define GSL_C 0.180336880111f   // SCALE * log2(e)

typedef short s16x4 __attribute__((ext_vector_type(4)));
typedef short s16x8 __attribute__((ext_vector_type(8)));
typedef float f32x4 __attribute__((ext_vector_type(4)));
typedef float f32x16 __attribute__((ext_vector_type(16)));

__device__ __forceinline__ unsigned short f2bf(float x){
  union { float f; unsigned int u; } v; v.f = x;
  unsigned int r = v.u + 0x7fffu + ((v.u >> 16) & 1u);
  return (unsigned short)(r >> 16);
}
__device__ __forceinline__ float bf2f(unsigned short u){
  union { unsigned int u; float f; } v; v.u = ((unsigned int)u) << 16;
  return v.f;
}
__device__ __forceinline__ f32x4 mfma16(s16x8 a, s16x8 b, f32x4 c){
  return __builtin_amdgcn_mfma_f32_16x16x32_bf16(a, b, c, 0, 0, 0);
}
__device__ __forceinline__ f32x16 mfma32(s16x8 a, s16x8 b, f32x16 c){
  return __builtin_amdgcn_mfma_f32_32x32x16_bf16(a, b, c, 0, 0, 0);
}
__device__ __forceinline__ void gld_lds16(const void* g, void* l){
  __builtin_amdgcn_global_load_lds(
      (const __attribute__((address_space(1))) unsigned int*)g,
      (__attribute__((address_space(3))) unsigned int*)l, 16, 0, 0);
}
__device__ __forceinline__ unsigned int cvtpk(float lo, float hi){
  unsigned int r;
  asm("v_cvt_pk_bf16_f32 %0, %1, %2" : "=v"(r) : "v"(lo), "v"(hi));
  return r;
}
__device__ __forceinline__ void plswap(unsigned int &a, unsigned int &b){
  asm("v_permlane32_swap_b32 %0, %1" : "+v"(a), "+v"(b));
}

// ---------------- prep: cast q -> bf16 (bid<2048) + W transpose (bid>=2048) ---
__global__ __launch_bounds__(256) void prep_kernel(const float* __restrict__ in,
    unsigned short* __restrict__ out,
    const float* __restrict__ W0, const float* __restrict__ W1,
    const float* __restrict__ W2, const float* __restrict__ W3,
    unsigned short* __restrict__ Wt){
  int bid = blockIdx.x;
  int tid = threadIdx.x;
  if (bid < 2048){
    int i = bid*256 + tid;
    const float4* p = (const float4*)in + (size_t)i*2;
    float4 a = p[0], b = p[1];
    unsigned short t[8] = {f2bf(a.x),f2bf(a.y),f2bf(a.z),f2bf(a.w),
                           f2bf(b.x),f2bf(b.y),f2bf(b.z),f2bf(b.w)};
    *(s16x8*)(out + (size_t)i*8) = *(const s16x8*)t;
  } else {
    int idx = bid - 2048;
    int z = idx >> 8, rem = idx & 255;
    int k0 = (rem & 15)*64, n0 = (rem >> 4)*64;
    const float* src = (z==0)?W0:(z==1)?W1:(z==2)?W2:W3;
    unsigned short* dst = Wt + (size_t)z*1048576;
    __shared__ unsigned short tile[64*72];
    int r = tid>>2, c = (tid&3)*16;
    const float* p = src + (size_t)(k0+r)*1024 + n0 + c;
    #pragma unroll
    for (int j=0;j<16;j++) tile[r*72 + c + j] = f2bf(p[j]);
    __syncthreads();
    int n = tid>>2, kc = (tid&3)*16;
    unsigned short o[16];
    #pragma unroll
    for (int j=0;j<16;j++) o[j] = tile[(kc+j)*72 + n];
    *(s16x8*)&dst[(size_t)(n0+n)*1024 + k0 + kc]     = *(const s16x8*)o;
    *(s16x8*)&dst[(size_t)(n0+n)*1024 + k0 + kc + 8] = *(const s16x8*)(o+8);
  }
}

// ---------------- 128x128xBK32 bf16 GEMM (projections) -----------------------
// TRIPLE-buffered (depth-2 prefetch) with COUNTED vmcnt + raw s_barrier:
// loads never drained in-loop (T3/T4). 48 KB LDS -> 3 blocks/CU.
// z<2 -> Qh/Kh heads layout + fused PRESCALED norms; z==2 -> Vt direct.
__global__ __launch_bounds__(512) void gemm_proj(const unsigned short* __restrict__ A,
    const unsigned short* __restrict__ Bt, unsigned short* __restrict__ outH,
    unsigned short* __restrict__ VtG,
    float* __restrict__ qn, float* __restrict__ kn, const float* __restrict__ gamma){
  __shared__ short As[3][4096];   // [128][32] per buffer
  __shared__ short Bs[3][4096];
  int tid = threadIdx.x;
  int w = tid>>6, l = tid&63;
  int lm = l & 15, hi = l >> 4;
  int wr = w>>1, wc = w&1;
  int m0 = blockIdx.x*128, n0 = blockIdx.y*128;

  const unsigned short* Bz = Bt + (size_t)(n0>>10)*1048576;
  int bn0 = n0 & 1023;

  f32x4 acc[2][4];
  #pragma unroll
  for (int r=0;r<2;r++)
    #pragma unroll
    for (int c=0;c<4;c++){ f32x4 z = {0.f,0.f,0.f,0.f}; acc[r][c] = z; }

  int srow = w*16 + (l>>2);
  int schk = ((l&3) ^ ((l>>3)&3))*8;
  const unsigned short* gA = A  + (size_t)(m0  + srow)*1024 + schk;
  const unsigned short* gB = Bz + (size_t)(bn0 + srow)*1024 + schk;

  int ch = (hi ^ ((lm>>1)&3))*8;

  // prologue: stage tiles 0 and 1 (4 loads in flight; no wait yet)
  gld_lds16(gA,      &As[0][w*512]);
  gld_lds16(gB,      &Bs[0][w*512]);
  gld_lds16(gA + 32, &As[1][w*512]);
  gld_lds16(gB + 32, &Bs[1][w*512]);

  const int NKT = 32;
  int cur = 0;
  for (int kt=0; kt<NKT; ++kt){
    // issue stage kt+2 into buffer (cur+2)%3 (== buffer read at kt-1; the
    // bottom barrier of kt-1 guarantees all waves are done with it)
    if (kt+2 < NKT){
      int wb = cur + 2; if (wb >= 3) wb -= 3;
      gld_lds16(gA + (size_t)(kt+2)*32, &As[wb][w*512]);
      gld_lds16(gB + (size_t)(kt+2)*32, &Bs[wb][w*512]);
    }
    // counted wait: stage kt complete; stages kt+1,kt+2 stay IN FLIGHT
    if (kt < NKT-2)       asm volatile("s_waitcnt vmcnt(4)" ::: "memory");
    else if (kt == NKT-2) asm volatile("s_waitcnt vmcnt(2)" ::: "memory");
    else                  asm volatile("s_waitcnt vmcnt(0)" ::: "memory");
    __builtin_amdgcn_s_barrier();   // all waves' stage-kt writes visible

    const short* cA = &As[cur][0];
    const short* cB = &Bs[cur][0];
    s16x8 af[2], bfv[4];
    #pragma unroll
    for (int r=0;r<2;r++)
      af[r]  = *(const s16x8*)(cA + (wr*32 + r*16 + lm)*32 + ch);
    #pragma unroll
    for (int c=0;c<4;c++)
      bfv[c] = *(const s16x8*)(cB + (wc*64 + c*16 + lm)*32 + ch);
    __builtin_amdgcn_s_setprio(1);
    #pragma unroll
    for (int r=0;r<2;r++)
      #pragma unroll
      for (int c=0;c<4;c++)
        acc[r][c] = mfma16(af[r], bfv[c], acc[r][c]);
    __builtin_amdgcn_s_setprio(0);
    __builtin_amdgcn_s_barrier();   // reads done before this buffer is re-staged
    cur = (cur + 1 < 3) ? cur + 1 : 0;
  }

  int z = n0 >> 10;
  if (z == 2){
    // --- V path: transpose 32t x 64d per wave through its private LDS tile ---
    short* tb = (w < 4) ? (&As[0][0] + w*2048) : (&Bs[0][0] + (w-4)*2048);
    #pragma unroll
    for (int r=0;r<2;r++)
      #pragma unroll
      for (int c=0;c<4;c++){
        unsigned short t4[4] = {f2bf(acc[r][c][0]), f2bf(acc[r][c][1]),
                                f2bf(acc[r][c][2]), f2bf(acc[r][c][3])};
        *(s16x4*)(tb + (c*16 + lm)*32 + r*16 + hi*4) = *(const s16x4*)t4;
      }
    int bq = m0 >> 11;
    int hq = (bn0 >> 6) + wc;
    int bh = bq*16 + hq;
    int t0w = (m0 & 2047) + wr*32;
    unsigned short* vt = VtG + (size_t)bh*131072;
    #pragma unroll
    for (int it=0; it<4; ++it){
      int d = (l>>2) + it*16;
      int tl = (l&3)*8;
      s16x8 vv = *(const s16x8*)(tb + d*32 + tl);
      *(s16x8*)(vt + (size_t)d*2048 + t0w + tl) = vv;
    }
  } else {
    unsigned short* oz = outH + (size_t)z*4194304;
    #pragma unroll
    for (int r=0;r<2;r++){
      #pragma unroll
      for (int i=0;i<4;i++){
        int m = m0 + wr*32 + r*16 + hi*4 + i;
        int bq = m >> 11, sq = m & 2047;
        float nrm = 0.f;
        #pragma unroll
        for (int c=0;c<4;c++){
          int nn = bn0 + wc*64 + c*16 + lm;
          int hq = nn >> 6, dq = nn & 63;
          int bh = bq*16 + hq;
          unsigned short bv = f2bf(acc[r][c][i]);
          oz[((size_t)bh*2048 + sq)*64 + dq] = bv;
          float vf = bf2f(bv);
          nrm = fmaf(vf, vf, nrm);
        }
        nrm += __shfl_xor(nrm, 1);
        nrm += __shfl_xor(nrm, 2);
        nrm += __shfl_xor(nrm, 4);
        nrm += __shfl_xor(nrm, 8);
        if (lm == 0){
          int hq = (bn0 + wc*64) >> 6;
          float gsl_h = gamma[hq] * GSL_C;
          float* dst = z ? kn : qn;
          dst[(size_t)(bq*16 + hq)*2048 + sq] = nrm * gsl_h;
        }
      }
    }
  }
}

// ---------------- Wo GEMM 128x64xBK64, dbuf, grid 512 (2 blocks/CU) ----------
__global__ __launch_bounds__(512) void gemm_out(const unsigned short* __restrict__ A,
    const unsigned short* __restrict__ Bt, float* __restrict__ outF){
  __shared__ short As[16384];   // 2 x [128][64]
  __shared__ short Bs[8192];    // 2 x [64][64]
  int tid = threadIdx.x;
  int w = tid>>6, l = tid&63;
  int lm = l & 15, hi = l >> 4;
  int wr = w>>1, wc = w&1;
  int m0 = blockIdx.x*128, n0 = blockIdx.y*64;

  f32x4 acc[2][2];
  #pragma unroll
  for (int r=0;r<2;r++)
    #pragma unroll
    for (int c=0;c<2;c++){ f32x4 z = {0.f,0.f,0.f,0.f}; acc[r][c] = z; }

  int rsub = l>>3, csw = ((l&7) ^ (l>>3))*8;
  const unsigned short* gA = A  + (size_t)(m0 + w*16 + rsub)*1024 + csw;
  const unsigned short* gB = Bt + (size_t)(n0 + w*8  + rsub)*1024 + csw;

  int ch0 = ((hi)     ^ (lm&7))*8;
  int ch1 = ((4 + hi) ^ (lm&7))*8;

  gld_lds16(gA,        As + w*1024);
  gld_lds16(gA + 8192, As + w*1024 + 512);
  gld_lds16(gB,        Bs + w*512);
  __syncthreads();

  const int NKT = 16;
  int buf = 0;
  for (int kt=0; kt<NKT; ++kt){
    if (kt+1 < NKT){
      const unsigned short* a = gA + (size_t)(kt+1)*64;
      const unsigned short* b = gB + (size_t)(kt+1)*64;
      gld_lds16(a,        As + (buf^1)*8192 + w*1024);
      gld_lds16(a + 8192, As + (buf^1)*8192 + w*1024 + 512);
      gld_lds16(b,        Bs + (buf^1)*4096 + w*512);
    }
    const short* curA = As + buf*8192;
    const short* curB = Bs + buf*4096;
    s16x8 af[2][2], bfv[2][2];
    #pragma unroll
    for (int r=0;r<2;r++){
      int ro = (wr*32 + r*16 + lm)*64;
      af[r][0] = *(const s16x8*)(curA + ro + ch0);
      af[r][1] = *(const s16x8*)(curA + ro + ch1);
    }
    #pragma unroll
    for (int c=0;c<2;c++){
      int ro = (wc*32 + c*16 + lm)*64;
      bfv[c][0] = *(const s16x8*)(curB + ro + ch0);
      bfv[c][1] = *(const s16x8*)(curB + ro + ch1);
    }
    __builtin_amdgcn_s_setprio(1);
    #pragma unroll
    for (int s=0;s<2;s++)
      #pragma unroll
      for (int r=0;r<2;r++)
        #pragma unroll
        for (int c=0;c<2;c++)
          acc[r][c] = mfma16(af[r][s], bfv[c][s], acc[r][c]);
    __builtin_amdgcn_s_setprio(0);
    __syncthreads();
    buf ^= 1;
  }

  #pragma unroll
  for (int r=0;r<2;r++)
    #pragma unroll
    for (int c=0;c<2;c++)
      #pragma unroll
      for (int i=0;i<4;i++){
        int m = m0 + wr*32 + r*16 + hi*4 + i;
        int n = n0 + wc*32 + c*16 + lm;
        outF[(size_t)m*1024 + n] = acc[r][c][i];
      }
}

// ---------------- attention (32x32 MFMA, in-reg P, tb-interleaved ILP) --------
#define JOB(si,ts,te,buf,zm) ((unsigned int)((si)|((ts)<<4)|((te)<<10)|((buf)<<16)|((zm)<<18)))
__device__ const unsigned int JOBS[32] = {
  JOB(0,0,11,0,0),   JOB(5,10,21,0,0),  JOB(0,22,32,2,0),  JOB(1,12,22,1,0),
  JOB(2,4,14,0,0),   JOB(6,22,32,1,2),  JOB(2,23,32,2,0),  JOB(7,14,23,0,0),
  JOB(0,11,22,1,0),  JOB(5,21,32,1,2),  JOB(1,2,12,0,0),   JOB(1,22,32,2,0),
  JOB(6,12,22,0,0),  JOB(2,14,23,1,0),  JOB(3,6,15,0,0),   JOB(7,23,32,1,2),
  JOB(11,22,32,0,3), JOB(3,24,32,2,0),  JOB(4,8,16,0,0),   JOB(4,16,24,1,0),
  JOB(4,24,32,2,0),  JOB(8,16,24,0,0),  JOB(3,15,24,1,0),  JOB(8,24,32,1,2),
  JOB(15,30,32,0,3), JOB(14,28,32,0,3), JOB(10,20,26,0,0), JOB(10,26,32,1,2),
  JOB(13,26,32,0,3), JOB(9,18,25,0,0),  JOB(9,25,32,1,2),  JOB(12,24,32,0,3)
};

__global__ __launch_bounds__(256, 4) void attn_kernel(const unsigned short* __restrict__ Qh,
    const unsigned short* __restrict__ Kh, const unsigned short* __restrict__ VtG,
    const float* __restrict__ qn, const float* __restrict__ kn,
    const float* __restrict__ gamma, unsigned short* __restrict__ aO0,
    unsigned short* __restrict__ aO1, unsigned short* __restrict__ aO2){
  __shared__ short Ks[2][4096];   // [t 64][d 64], chunk-swizzled
  __shared__ short Vs[2][4096];   // [d 64][t 64], chunk-swizzled

  int bid = blockIdx.x;
  int bh = bid & 31; int b = bh>>4, h = bh&15;
  unsigned int e = JOBS[bid >> 5];
  int si2 = e & 15, ts = (e>>4)&63, te = (e>>10)&63, bsel = (e>>16)&3, zm = (e>>18)&3;
  int s0 = si2*128;

  int tid = threadIdx.x, w = tid>>6, l = tid&63;
  int l31 = l & 31, hi5 = l >> 5, l7 = l & 7;
  float gs2l = 2.f * gamma[h] * GSL_C;

  int q0 = s0 + w*32;            // wave's 32 q-rows
  int qrow = q0 + l31;
  const unsigned short* qb = Qh + ((size_t)bh*2048 + qrow)*64;
  s16x8 qf[4];
  #pragma unroll
  for (int c=0;c<4;c++) qf[c] = *(const s16x8*)(qb + c*16 + hi5*8);
  float gq = -qn[(size_t)bh*2048 + qrow];   // prescaled
  const float* knp = kn + (size_t)bh*2048;

  int chs = (l7 ^ (l>>3))*8;
  const unsigned short* kp0 = Kh  + ((size_t)bh*2048 + w*8 + (l>>3))*64 + chs;
  const unsigned short* vp0 = VtG + ((size_t)bh*64 + w*8 + (l>>3))*2048 + chs;

  f32x16 accO0, accO1;
  #pragma unroll
  for (int r=0;r<16;r++){ accO0[r] = 0.f; accO1[r] = 0.f; }

#define STAGE(bufi, tabs) { \
    const unsigned short* kp = kp0 + (size_t)(tabs)*64; \
    const unsigned short* vp = vp0 + (tabs); \
    short* dK = &Ks[bufi][w*512]; \
    short* dV = &Vs[bufi][w*512]; \
    gld_lds16(kp,           dK); \
    gld_lds16(kp + 32*64,   dK + 2048); \
    gld_lds16(vp,           dV); \
    gld_lds16(vp + 32*2048, dV + 2048); \
  }

  STAGE(0, ts*64);
  __syncthreads();

  int cur = 0;
  for (int tt = ts; tt < te; ++tt, cur ^= 1){
    int t0 = tt*64;
    if (tt + 1 < te) STAGE(cur^1, (tt+1)*64);
    const short* kb = &Ks[cur][0];
    const short* vb = &Vs[cur][0];

    // ---- phase 1: QK for both 32-blocks ----
    f32x16 sc2[2];
    #pragma unroll
    for (int tb=0; tb<2; tb++){
      int tbase = t0 + tb*32 - s0;
      if (tbase + 31 <= w*32) continue;     // fully masked: skip
      f32x16 sc;
      #pragma unroll
      for (int r=0;r<16;r++) sc[r] = 0.f;
      __builtin_amdgcn_s_setprio(1);
      #pragma unroll
      for (int c=0;c<4;c++){
        s16x8 kf = *(const s16x8*)(kb + (tb*32 + l31)*64 + (((2*c + hi5) ^ l7)*8));
        sc = mfma32(kf, qf[c], sc);
      }
      __builtin_amdgcn_s_setprio(0);
      sc2[tb] = sc;
    }

    // ---- phase 2: transform + PV per block ----
    #pragma unroll
    for (int tb=0; tb<2; tb++){
      int tbase = t0 + tb*32 - s0;
      if (tbase + 31 <= w*32) continue;
      f32x16 sc = sc2[tb];
      float ev[16];
      #pragma unroll
      for (int gg=0; gg<4; gg++){
        float4 knv = *(const float4*)(knp + t0 + tb*32 + gg*8 + hi5*4);
        float ks4[4] = {knv.x, knv.y, knv.z, knv.w};
        #pragma unroll
        for (int i=0;i<4;i++){
          int r = gg*4 + i;
          ev[r] = __builtin_amdgcn_exp2f(fminf(fmaf(gs2l, sc[r], gq - ks4[i]), 0.f));
        }
      }
      if (tbase < w*32 + 32){               // partial mask (strict upper: keep t>q)
        #pragma unroll
        for (int r=0;r<16;r++){
          int t = t0 + tb*32 + (r&3) + 8*(r>>2) + 4*hi5;
          ev[r] = (t > qrow) ? ev[r] : 0.f;
        }
      }
      unsigned int u0 = cvtpk(ev[0],  ev[1]),  u1 = cvtpk(ev[2],  ev[3]);
      unsigned int u2 = cvtpk(ev[4],  ev[5]),  u3 = cvtpk(ev[6],  ev[7]);
      unsigned int u4 = cvtpk(ev[8],  ev[9]),  u5 = cvtpk(ev[10], ev[11]);
      unsigned int u6 = cvtpk(ev[12], ev[13]), u7 = cvtpk(ev[14], ev[15]);
      plswap(u0, u2);
      plswap(u1, u3);
      plswap(u4, u6);
      plswap(u5, u7);
      unsigned int f0[4] = {u0, u1, u2, u3};
      unsigned int f1[4] = {u4, u5, u6, u7};
      s16x8 pa0 = *(const s16x8*)f0;
      s16x8 pa1 = *(const s16x8*)f1;
      __builtin_amdgcn_s_setprio(1);
      {
        int cg0 = 2*tb, cg1 = 2*tb + 1;
        s16x8 v00 = *(const s16x8*)(vb + (l31)*64      + (((2*cg0 + hi5) ^ l7)*8));
        s16x8 v01 = *(const s16x8*)(vb + (l31)*64      + (((2*cg1 + hi5) ^ l7)*8));
        s16x8 v10 = *(const s16x8*)(vb + (32 + l31)*64 + (((2*cg0 + hi5) ^ l7)*8));
        s16x8 v11 = *(const s16x8*)(vb + (32 + l31)*64 + (((2*cg1 + hi5) ^ l7)*8));
        accO0 = mfma32(pa0, v00, accO0);
        accO0 = mfma32(pa1, v01, accO0);
        accO1 = mfma32(pa0, v10, accO1);
        accO1 = mfma32(pa1, v11, accO1);
      }
      __builtin_amdgcn_s_setprio(0);
    }
    __syncthreads();
  }
#undef STAGE

  unsigned short* aoP = (bsel==0) ? aO0 : (bsel==1) ? aO1 : aO2;
  #pragma unroll
  for (int r=0;r<16;r++){
    int s = q0 + (r&3) + 8*(r>>2) + 4*hi5;
    size_t base = ((size_t)b*2048 + s)*1024 + h*64;
    aoP[base + l31]      = f2bf(accO0[r]);
    aoP[base + 32 + l31] = f2bf(accO1[r]);
  }
  if (zm){
    s16x8 zz8 = {0,0,0,0,0,0,0,0};
    int zr = tid >> 1, zc = (tid & 1)*32;
    size_t zbase = ((size_t)b*2048 + s0 + zr)*1024 + h*64 + zc;
    if (zm & 1){
      #pragma unroll
      for (int j=0;j<4;j++) *(s16x8*)&aO1[zbase + j*8] = zz8;
    }
    if (zm & 2){
      #pragma unroll
      for (int j=0;j<4;j++) *(s16x8*)&aO2[zbase + j*8] = zz8;
    }
  }
}

// ---------------- sum of 3 bf16 partial buffers -> aO0 ----------------
__global__ __launch_bounds__(256) void sum3_kernel(unsigned short* __restrict__ a,
    const unsigned short* __restrict__ bsrc, const unsigned short* __restrict__ csrc){
  size_t i = ((size_t)blockIdx.x*256 + threadIdx.x)*8;
  s16x8 va = *(const s16x8*)(a + i);
  s16x8 vb = *(const s16x8*)(bsrc + i);
  s16x8 vc = *(const s16x8*)(csrc + i);
  unsigned short o[8];
  #pragma unroll
  for (int j=0;j<8;j++)
    o[j] = f2bf(bf2f((unsigned short)va[j]) + bf2f((unsigned short)vb[j])
                + bf2f((unsigned short)vc[j]));
  *(s16x8*)(a + i) = *(const s16x8*)o;
}

extern "C" void kernel_launch(void* const* d_in, const int* in_sizes, int n_in,
                              void* d_out, int out_size, void* d_ws, size_t ws_size,
                              hipStream_t stream){
  const float* q  = (const float*)d_in[0];
  const float* Wq = (const float*)d_in[1];
  const float* Wk = (const float*)d_in[2];
  const float* Wv = (const float*)d_in[3];
  const float* Wo = (const float*)d_in[4];
  const float* gm = (const float*)d_in[5];
  float* out = (float*)d_out;

  unsigned short* qbf = (unsigned short*)d_ws;  // dead after gemm_proj -> aO1
  unsigned short* Wt  = qbf + 4194304;          // 4 x [1024][1024] bf16 (B^T form)
  unsigned short* Qh  = Wt  + 4194304;          // [bh][2048][64]
  unsigned short* Kh  = Qh  + 4194304;
  unsigned short* Vh  = Kh  + 4194304;          // aO2 (partial buffer)
  unsigned short* Vt  = Vh  + 4194304;          // [bh][64][2048], written by gemm_proj
  unsigned short* aO  = Vt  + 4194304;          // partial 0 + final sum
  float* qn = (float*)(aO + 4194304);           // [bh*2048], prescaled
  float* kn = qn + 65536;

  unsigned short* aO1 = qbf;
  unsigned short* aO2 = Vh;

  prep_kernel  <<<dim3(3072), 256, 0, stream>>>(q, qbf, Wq, Wk, Wv, Wo, Wt);
  gemm_proj    <<<dim3(32,24), 512, 0, stream>>>(qbf, Wt, Qh, Vt, qn, kn, gm);
  attn_kernel  <<<dim3(1024), 256, 0, stream>>>(Qh, Kh, Vt, qn, kn, gm, aO, aO1, aO2);
  sum3_kernel  <<<dim3(2048), 256, 0, stream>>>(aO, aO1, aO2);
  gemm_out     <<<dim3(32,16), 512, 0, stream>>>(aO, Wt + 3*1048576, out);
}

// Round 19
// 99.880 us; speedup vs baseline: 1.0518x; 1.0073x over previous
//
#include <hip/hip_runtime.h>
#include <stdint.h>

#define SCALE 0.125f   // 1/sqrt(64)
#define GSL_C 0.180336880111f   // SCALE * log2(e)

typedef short s16x4 __attribute__((ext_vector_type(4)));
typedef short s16x8 __attribute__((ext_vector_type(8)));
typedef float f32x4 __attribute__((ext_vector_type(4)));
typedef float f32x16 __attribute__((ext_vector_type(16)));

__device__ __forceinline__ unsigned short f2bf(float x){
  union { float f; unsigned int u; } v; v.f = x;
  unsigned int r = v.u + 0x7fffu + ((v.u >> 16) & 1u);
  return (unsigned short)(r >> 16);
}
__device__ __forceinline__ float bf2f(unsigned short u){
  union { unsigned int u; float f; } v; v.u = ((unsigned int)u) << 16;
  return v.f;
}
__device__ __forceinline__ f32x4 mfma16(s16x8 a, s16x8 b, f32x4 c){
  return __builtin_amdgcn_mfma_f32_16x16x32_bf16(a, b, c, 0, 0, 0);
}
__device__ __forceinline__ f32x16 mfma32(s16x8 a, s16x8 b, f32x16 c){
  return __builtin_amdgcn_mfma_f32_32x32x16_bf16(a, b, c, 0, 0, 0);
}
__device__ __forceinline__ void gld_lds16(const void* g, void* l){
  __builtin_amdgcn_global_load_lds(
      (const __attribute__((address_space(1))) unsigned int*)g,
      (__attribute__((address_space(3))) unsigned int*)l, 16, 0, 0);
}
__device__ __forceinline__ unsigned int cvtpk(float lo, float hi){
  unsigned int r;
  asm("v_cvt_pk_bf16_f32 %0, %1, %2" : "=v"(r) : "v"(lo), "v"(hi));
  return r;
}
__device__ __forceinline__ void plswap(unsigned int &a, unsigned int &b){
  asm("v_permlane32_swap_b32 %0, %1" : "+v"(a), "+v"(b));
}

// ---------------- prep: cast q -> bf16 (bid<2048) + W transpose (bid>=2048) ---
__global__ __launch_bounds__(256) void prep_kernel(const float* __restrict__ in,
    unsigned short* __restrict__ out,
    const float* __restrict__ W0, const float* __restrict__ W1,
    const float* __restrict__ W2, const float* __restrict__ W3,
    unsigned short* __restrict__ Wt){
  int bid = blockIdx.x;
  int tid = threadIdx.x;
  if (bid < 2048){
    int i = bid*256 + tid;
    const float4* p = (const float4*)in + (size_t)i*2;
    float4 a = p[0], b = p[1];
    unsigned short t[8] = {f2bf(a.x),f2bf(a.y),f2bf(a.z),f2bf(a.w),
                           f2bf(b.x),f2bf(b.y),f2bf(b.z),f2bf(b.w)};
    *(s16x8*)(out + (size_t)i*8) = *(const s16x8*)t;
  } else {
    int idx = bid - 2048;
    int z = idx >> 8, rem = idx & 255;
    int k0 = (rem & 15)*64, n0 = (rem >> 4)*64;
    const float* src = (z==0)?W0:(z==1)?W1:(z==2)?W2:W3;
    unsigned short* dst = Wt + (size_t)z*1048576;
    __shared__ unsigned short tile[64*72];
    int r = tid>>2, c = (tid&3)*16;
    const float* p = src + (size_t)(k0+r)*1024 + n0 + c;
    #pragma unroll
    for (int j=0;j<16;j++) tile[r*72 + c + j] = f2bf(p[j]);
    __syncthreads();
    int n = tid>>2, kc = (tid&3)*16;
    unsigned short o[16];
    #pragma unroll
    for (int j=0;j<16;j++) o[j] = tile[(kc+j)*72 + n];
    *(s16x8*)&dst[(size_t)(n0+n)*1024 + k0 + kc]     = *(const s16x8*)o;
    *(s16x8*)&dst[(size_t)(n0+n)*1024 + k0 + kc + 8] = *(const s16x8*)(o+8);
  }
}

// ---------------- 128x128xBK32 bf16 GEMM (projections) -----------------------
// TRIPLE-buffered (depth-2 prefetch) with COUNTED vmcnt + raw s_barrier.
// z<2 -> Qh/Kh heads layout + fused PRESCALED norms; z==2 -> Vt direct.
__global__ __launch_bounds__(512) void gemm_proj(const unsigned short* __restrict__ A,
    const unsigned short* __restrict__ Bt, unsigned short* __restrict__ outH,
    unsigned short* __restrict__ VtG,
    float* __restrict__ qn, float* __restrict__ kn, const float* __restrict__ gamma){
  __shared__ short As[3][4096];   // [128][32] per buffer
  __shared__ short Bs[3][4096];
  int tid = threadIdx.x;
  int w = tid>>6, l = tid&63;
  int lm = l & 15, hi = l >> 4;
  int wr = w>>1, wc = w&1;
  int m0 = blockIdx.x*128, n0 = blockIdx.y*128;

  const unsigned short* Bz = Bt + (size_t)(n0>>10)*1048576;
  int bn0 = n0 & 1023;

  f32x4 acc[2][4];
  #pragma unroll
  for (int r=0;r<2;r++)
    #pragma unroll
    for (int c=0;c<4;c++){ f32x4 z = {0.f,0.f,0.f,0.f}; acc[r][c] = z; }

  int srow = w*16 + (l>>2);
  int schk = ((l&3) ^ ((l>>3)&3))*8;
  const unsigned short* gA = A  + (size_t)(m0  + srow)*1024 + schk;
  const unsigned short* gB = Bz + (size_t)(bn0 + srow)*1024 + schk;

  int ch = (hi ^ ((lm>>1)&3))*8;

  // prologue: stage tiles 0 and 1 (4 loads in flight; no wait yet)
  gld_lds16(gA,      &As[0][w*512]);
  gld_lds16(gB,      &Bs[0][w*512]);
  gld_lds16(gA + 32, &As[1][w*512]);
  gld_lds16(gB + 32, &Bs[1][w*512]);

  const int NKT = 32;
  int cur = 0;
  for (int kt=0; kt<NKT; ++kt){
    if (kt+2 < NKT){
      int wb = cur + 2; if (wb >= 3) wb -= 3;
      gld_lds16(gA + (size_t)(kt+2)*32, &As[wb][w*512]);
      gld_lds16(gB + (size_t)(kt+2)*32, &Bs[wb][w*512]);
    }
    if (kt < NKT-2)       asm volatile("s_waitcnt vmcnt(4)" ::: "memory");
    else if (kt == NKT-2) asm volatile("s_waitcnt vmcnt(2)" ::: "memory");
    else                  asm volatile("s_waitcnt vmcnt(0)" ::: "memory");
    __builtin_amdgcn_s_barrier();   // all waves' stage-kt writes visible

    const short* cA = &As[cur][0];
    const short* cB = &Bs[cur][0];
    s16x8 af[2], bfv[4];
    #pragma unroll
    for (int r=0;r<2;r++)
      af[r]  = *(const s16x8*)(cA + (wr*32 + r*16 + lm)*32 + ch);
    #pragma unroll
    for (int c=0;c<4;c++)
      bfv[c] = *(const s16x8*)(cB + (wc*64 + c*16 + lm)*32 + ch);
    __builtin_amdgcn_s_setprio(1);
    #pragma unroll
    for (int r=0;r<2;r++)
      #pragma unroll
      for (int c=0;c<4;c++)
        acc[r][c] = mfma16(af[r], bfv[c], acc[r][c]);
    __builtin_amdgcn_s_setprio(0);
    __builtin_amdgcn_s_barrier();   // reads done before this buffer is re-staged
    cur = (cur + 1 < 3) ? cur + 1 : 0;
  }

  int z = n0 >> 10;
  if (z == 2){
    // --- V path: transpose 32t x 64d per wave through its private LDS tile ---
    short* tb = (w < 4) ? (&As[0][0] + w*2048) : (&Bs[0][0] + (w-4)*2048);
    #pragma unroll
    for (int r=0;r<2;r++)
      #pragma unroll
      for (int c=0;c<4;c++){
        unsigned short t4[4] = {f2bf(acc[r][c][0]), f2bf(acc[r][c][1]),
                                f2bf(acc[r][c][2]), f2bf(acc[r][c][3])};
        *(s16x4*)(tb + (c*16 + lm)*32 + r*16 + hi*4) = *(const s16x4*)t4;
      }
    int bq = m0 >> 11;
    int hq = (bn0 >> 6) + wc;
    int bh = bq*16 + hq;
    int t0w = (m0 & 2047) + wr*32;
    unsigned short* vt = VtG + (size_t)bh*131072;
    #pragma unroll
    for (int it=0; it<4; ++it){
      int d = (l>>2) + it*16;
      int tl = (l&3)*8;
      s16x8 vv = *(const s16x8*)(tb + d*32 + tl);
      *(s16x8*)(vt + (size_t)d*2048 + t0w + tl) = vv;
    }
  } else {
    unsigned short* oz = outH + (size_t)z*4194304;
    #pragma unroll
    for (int r=0;r<2;r++){
      #pragma unroll
      for (int i=0;i<4;i++){
        int m = m0 + wr*32 + r*16 + hi*4 + i;
        int bq = m >> 11, sq = m & 2047;
        float nrm = 0.f;
        #pragma unroll
        for (int c=0;c<4;c++){
          int nn = bn0 + wc*64 + c*16 + lm;
          int hq = nn >> 6, dq = nn & 63;
          int bh = bq*16 + hq;
          unsigned short bv = f2bf(acc[r][c][i]);
          oz[((size_t)bh*2048 + sq)*64 + dq] = bv;
          float vf = bf2f(bv);
          nrm = fmaf(vf, vf, nrm);
        }
        nrm += __shfl_xor(nrm, 1);
        nrm += __shfl_xor(nrm, 2);
        nrm += __shfl_xor(nrm, 4);
        nrm += __shfl_xor(nrm, 8);
        if (lm == 0){
          int hq = (bn0 + wc*64) >> 6;
          float gsl_h = gamma[hq] * GSL_C;
          float* dst = z ? kn : qn;
          dst[(size_t)(bq*16 + hq)*2048 + sq] = nrm * gsl_h;
        }
      }
    }
  }
}

// ---------------- Wo GEMM 128x64xBK64, TRIPLE-buffered counted vmcnt ----------
// Same T3/T4 structure as gemm_proj: depth-2 prefetch, raw barriers, loads
// never drained in-loop. 72 KB LDS; grid 512 = 2 blocks/CU (unchanged).
__global__ __launch_bounds__(512) void gemm_out(const unsigned short* __restrict__ A,
    const unsigned short* __restrict__ Bt, float* __restrict__ outF){
  __shared__ short As[3][8192];   // [128][64] per buffer
  __shared__ short Bs[3][4096];   // [64][64] per buffer
  int tid = threadIdx.x;
  int w = tid>>6, l = tid&63;
  int lm = l & 15, hi = l >> 4;
  int wr = w>>1, wc = w&1;
  int m0 = blockIdx.x*128, n0 = blockIdx.y*64;

  f32x4 acc[2][2];
  #pragma unroll
  for (int r=0;r<2;r++)
    #pragma unroll
    for (int c=0;c<2;c++){ f32x4 z = {0.f,0.f,0.f,0.f}; acc[r][c] = z; }

  int rsub = l>>3, csw = ((l&7) ^ (l>>3))*8;
  const unsigned short* gA = A  + (size_t)(m0 + w*16 + rsub)*1024 + csw;
  const unsigned short* gB = Bt + (size_t)(n0 + w*8  + rsub)*1024 + csw;

  int ch0 = ((hi)     ^ (lm&7))*8;
  int ch1 = ((4 + hi) ^ (lm&7))*8;

  // prologue: stage tiles 0 and 1 (6 loads in flight; no wait)
  gld_lds16(gA,             &As[0][w*1024]);
  gld_lds16(gA + 8192,      &As[0][w*1024 + 512]);
  gld_lds16(gB,             &Bs[0][w*512]);
  gld_lds16(gA + 64,        &As[1][w*1024]);
  gld_lds16(gA + 8192 + 64, &As[1][w*1024 + 512]);
  gld_lds16(gB + 64,        &Bs[1][w*512]);

  const int NKT = 16;
  int cur = 0;
  for (int kt=0; kt<NKT; ++kt){
    if (kt+2 < NKT){
      int wb = cur + 2; if (wb >= 3) wb -= 3;
      const unsigned short* a = gA + (size_t)(kt+2)*64;
      const unsigned short* b = gB + (size_t)(kt+2)*64;
      gld_lds16(a,        &As[wb][w*1024]);
      gld_lds16(a + 8192, &As[wb][w*1024 + 512]);
      gld_lds16(b,        &Bs[wb][w*512]);
    }
    if (kt < NKT-2)       asm volatile("s_waitcnt vmcnt(6)" ::: "memory");
    else if (kt == NKT-2) asm volatile("s_waitcnt vmcnt(3)" ::: "memory");
    else                  asm volatile("s_waitcnt vmcnt(0)" ::: "memory");
    __builtin_amdgcn_s_barrier();

    const short* curA = &As[cur][0];
    const short* curB = &Bs[cur][0];
    s16x8 af[2][2], bfv[2][2];
    #pragma unroll
    for (int r=0;r<2;r++){
      int ro = (wr*32 + r*16 + lm)*64;
      af[r][0] = *(const s16x8*)(curA + ro + ch0);
      af[r][1] = *(const s16x8*)(curA + ro + ch1);
    }
    #pragma unroll
    for (int c=0;c<2;c++){
      int ro = (wc*32 + c*16 + lm)*64;
      bfv[c][0] = *(const s16x8*)(curB + ro + ch0);
      bfv[c][1] = *(const s16x8*)(curB + ro + ch1);
    }
    __builtin_amdgcn_s_setprio(1);
    #pragma unroll
    for (int s=0;s<2;s++)
      #pragma unroll
      for (int r=0;r<2;r++)
        #pragma unroll
        for (int c=0;c<2;c++)
          acc[r][c] = mfma16(af[r][s], bfv[c][s], acc[r][c]);
    __builtin_amdgcn_s_setprio(0);
    __builtin_amdgcn_s_barrier();
    cur = (cur + 1 < 3) ? cur + 1 : 0;
  }

  #pragma unroll
  for (int r=0;r<2;r++)
    #pragma unroll
    for (int c=0;c<2;c++)
      #pragma unroll
      for (int i=0;i<4;i++){
        int m = m0 + wr*32 + r*16 + hi*4 + i;
        int n = n0 + wc*32 + c*16 + lm;
        outF[(size_t)m*1024 + n] = acc[r][c][i];
      }
}

// ---------------- attention (32x32 MFMA, in-reg P, tb-interleaved ILP) --------
#define JOB(si,ts,te,buf,zm) ((unsigned int)((si)|((ts)<<4)|((te)<<10)|((buf)<<16)|((zm)<<18)))
__device__ const unsigned int JOBS[32] = {
  JOB(0,0,11,0,0),   JOB(5,10,21,0,0),  JOB(0,22,32,2,0),  JOB(1,12,22,1,0),
  JOB(2,4,14,0,0),   JOB(6,22,32,1,2),  JOB(2,23,32,2,0),  JOB(7,14,23,0,0),
  JOB(0,11,22,1,0),  JOB(5,21,32,1,2),  JOB(1,2,12,0,0),   JOB(1,22,32,2,0),
  JOB(6,12,22,0,0),  JOB(2,14,23,1,0),  JOB(3,6,15,0,0),   JOB(7,23,32,1,2),
  JOB(11,22,32,0,3), JOB(3,24,32,2,0),  JOB(4,8,16,0,0),   JOB(4,16,24,1,0),
  JOB(4,24,32,2,0),  JOB(8,16,24,0,0),  JOB(3,15,24,1,0),  JOB(8,24,32,1,2),
  JOB(15,30,32,0,3), JOB(14,28,32,0,3), JOB(10,20,26,0,0), JOB(10,26,32,1,2),
  JOB(13,26,32,0,3), JOB(9,18,25,0,0),  JOB(9,25,32,1,2),  JOB(12,24,32,0,3)
};

__global__ __launch_bounds__(256, 4) void attn_kernel(const unsigned short* __restrict__ Qh,
    const unsigned short* __restrict__ Kh, const unsigned short* __restrict__ VtG,
    const float* __restrict__ qn, const float* __restrict__ kn,
    const float* __restrict__ gamma, unsigned short* __restrict__ aO0,
    unsigned short* __restrict__ aO1, unsigned short* __restrict__ aO2){
  __shared__ short Ks[2][4096];   // [t 64][d 64], chunk-swizzled
  __shared__ short Vs[2][4096];   // [d 64][t 64], chunk-swizzled

  int bid = blockIdx.x;
  int bh = bid & 31; int b = bh>>4, h = bh&15;
  unsigned int e = JOBS[bid >> 5];
  int si2 = e & 15, ts = (e>>4)&63, te = (e>>10)&63, bsel = (e>>16)&3, zm = (e>>18)&3;
  int s0 = si2*128;

  int tid = threadIdx.x, w = tid>>6, l = tid&63;
  int l31 = l & 31, hi5 = l >> 5, l7 = l & 7;
  float gs2l = 2.f * gamma[h] * GSL_C;

  int q0 = s0 + w*32;            // wave's 32 q-rows
  int qrow = q0 + l31;
  const unsigned short* qb = Qh + ((size_t)bh*2048 + qrow)*64;
  s16x8 qf[4];
  #pragma unroll
  for (int c=0;c<4;c++) qf[c] = *(const s16x8*)(qb + c*16 + hi5*8);
  float gq = -qn[(size_t)bh*2048 + qrow];   // prescaled
  const float* knp = kn + (size_t)bh*2048;

  int chs = (l7 ^ (l>>3))*8;
  const unsigned short* kp0 = Kh  + ((size_t)bh*2048 + w*8 + (l>>3))*64 + chs;
  const unsigned short* vp0 = VtG + ((size_t)bh*64 + w*8 + (l>>3))*2048 + chs;

  f32x16 accO0, accO1;
  #pragma unroll
  for (int r=0;r<16;r++){ accO0[r] = 0.f; accO1[r] = 0.f; }

#define STAGE(bufi, tabs) { \
    const unsigned short* kp = kp0 + (size_t)(tabs)*64; \
    const unsigned short* vp = vp0 + (tabs); \
    short* dK = &Ks[bufi][w*512]; \
    short* dV = &Vs[bufi][w*512]; \
    gld_lds16(kp,           dK); \
    gld_lds16(kp + 32*64,   dK + 2048); \
    gld_lds16(vp,           dV); \
    gld_lds16(vp + 32*2048, dV + 2048); \
  }

  STAGE(0, ts*64);
  __syncthreads();

  int cur = 0;
  for (int tt = ts; tt < te; ++tt, cur ^= 1){
    int t0 = tt*64;
    if (tt + 1 < te) STAGE(cur^1, (tt+1)*64);
    const short* kb = &Ks[cur][0];
    const short* vb = &Vs[cur][0];

    // ---- phase 1: QK for both 32-blocks ----
    f32x16 sc2[2];
    #pragma unroll
    for (int tb=0; tb<2; tb++){
      int tbase = t0 + tb*32 - s0;
      if (tbase + 31 <= w*32) continue;     // fully masked: skip
      f32x16 sc;
      #pragma unroll
      for (int r=0;r<16;r++) sc[r] = 0.f;
      __builtin_amdgcn_s_setprio(1);
      #pragma unroll
      for (int c=0;c<4;c++){
        s16x8 kf = *(const s16x8*)(kb + (tb*32 + l31)*64 + (((2*c + hi5) ^ l7)*8));
        sc = mfma32(kf, qf[c], sc);
      }
      __builtin_amdgcn_s_setprio(0);
      sc2[tb] = sc;
    }

    // ---- phase 2: transform + PV per block ----
    #pragma unroll
    for (int tb=0; tb<2; tb++){
      int tbase = t0 + tb*32 - s0;
      if (tbase + 31 <= w*32) continue;
      f32x16 sc = sc2[tb];
      float ev[16];
      #pragma unroll
      for (int gg=0; gg<4; gg++){
        float4 knv = *(const float4*)(knp + t0 + tb*32 + gg*8 + hi5*4);
        float ks4[4] = {knv.x, knv.y, knv.z, knv.w};
        #pragma unroll
        for (int i=0;i<4;i++){
          int r = gg*4 + i;
          ev[r] = __builtin_amdgcn_exp2f(fminf(fmaf(gs2l, sc[r], gq - ks4[i]), 0.f));
        }
      }
      if (tbase < w*32 + 32){               // partial mask (strict upper: keep t>q)
        #pragma unroll
        for (int r=0;r<16;r++){
          int t = t0 + tb*32 + (r&3) + 8*(r>>2) + 4*hi5;
          ev[r] = (t > qrow) ? ev[r] : 0.f;
        }
      }
      unsigned int u0 = cvtpk(ev[0],  ev[1]),  u1 = cvtpk(ev[2],  ev[3]);
      unsigned int u2 = cvtpk(ev[4],  ev[5]),  u3 = cvtpk(ev[6],  ev[7]);
      unsigned int u4 = cvtpk(ev[8],  ev[9]),  u5 = cvtpk(ev[10], ev[11]);
      unsigned int u6 = cvtpk(ev[12], ev[13]), u7 = cvtpk(ev[14], ev[15]);
      plswap(u0, u2);
      plswap(u1, u3);
      plswap(u4, u6);
      plswap(u5, u7);
      unsigned int f0[4] = {u0, u1, u2, u3};
      unsigned int f1[4] = {u4, u5, u6, u7};
      s16x8 pa0 = *(const s16x8*)f0;
      s16x8 pa1 = *(const s16x8*)f1;
      __builtin_amdgcn_s_setprio(1);
      {
        int cg0 = 2*tb, cg1 = 2*tb + 1;
        s16x8 v00 = *(const s16x8*)(vb + (l31)*64      + (((2*cg0 + hi5) ^ l7)*8));
        s16x8 v01 = *(const s16x8*)(vb + (l31)*64      + (((2*cg1 + hi5) ^ l7)*8));
        s16x8 v10 = *(const s16x8*)(vb + (32 + l31)*64 + (((2*cg0 + hi5) ^ l7)*8));
        s16x8 v11 = *(const s16x8*)(vb + (32 + l31)*64 + (((2*cg1 + hi5) ^ l7)*8));
        accO0 = mfma32(pa0, v00, accO0);
        accO0 = mfma32(pa1, v01, accO0);
        accO1 = mfma32(pa0, v10, accO1);
        accO1 = mfma32(pa1, v11, accO1);
      }
      __builtin_amdgcn_s_setprio(0);
    }
    __syncthreads();
  }
#undef STAGE

  unsigned short* aoP = (bsel==0) ? aO0 : (bsel==1) ? aO1 : aO2;
  #pragma unroll
  for (int r=0;r<16;r++){
    int s = q0 + (r&3) + 8*(r>>2) + 4*hi5;
    size_t base = ((size_t)b*2048 + s)*1024 + h*64;
    aoP[base + l31]      = f2bf(accO0[r]);
    aoP[base + 32 + l31] = f2bf(accO1[r]);
  }
  if (zm){
    s16x8 zz8 = {0,0,0,0,0,0,0,0};
    int zr = tid >> 1, zc = (tid & 1)*32;
    size_t zbase = ((size_t)b*2048 + s0 + zr)*1024 + h*64 + zc;
    if (zm & 1){
      #pragma unroll
      for (int j=0;j<4;j++) *(s16x8*)&aO1[zbase + j*8] = zz8;
    }
    if (zm & 2){
      #pragma unroll
      for (int j=0;j<4;j++) *(s16x8*)&aO2[zbase + j*8] = zz8;
    }
  }
}

// ---------------- sum of 3 bf16 partial buffers -> aO0 ----------------
__global__ __launch_bounds__(256) void sum3_kernel(unsigned short* __restrict__ a,
    const unsigned short* __restrict__ bsrc, const unsigned short* __restrict__ csrc){
  size_t i = ((size_t)blockIdx.x*256 + threadIdx.x)*8;
  s16x8 va = *(const s16x8*)(a + i);
  s16x8 vb = *(const s16x8*)(bsrc + i);
  s16x8 vc = *(const s16x8*)(csrc + i);
  unsigned short o[8];
  #pragma unroll
  for (int j=0;j<8;j++)
    o[j] = f2bf(bf2f((unsigned short)va[j]) + bf2f((unsigned short)vb[j])
                + bf2f((unsigned short)vc[j]));
  *(s16x8*)(a + i) = *(const s16x8*)o;
}

extern "C" void kernel_launch(void* const* d_in, const int* in_sizes, int n_in,
                              void* d_out, int out_size, void* d_ws, size_t ws_size,
                              hipStream_t stream){
  const float* q  = (const float*)d_in[0];
  const float* Wq = (const float*)d_in[1];
  const float* Wk = (const float*)d_in[2];
  const float* Wv = (const float*)d_in[3];
  const float* Wo = (const float*)d_in[4];
  const float* gm = (const float*)d_in[5];
  float* out = (float*)d_out;

  unsigned short* qbf = (unsigned short*)d_ws;  // dead after gemm_proj -> aO1
  unsigned short* Wt  = qbf + 4194304;          // 4 x [1024][1024] bf16 (B^T form)
  unsigned short* Qh  = Wt  + 4194304;          // [bh][2048][64]
  unsigned short* Kh  = Qh  + 4194304;
  unsigned short* Vh  = Kh  + 4194304;          // aO2 (partial buffer)
  unsigned short* Vt  = Vh  + 4194304;          // [bh][64][2048], written by gemm_proj
  unsigned short* aO  = Vt  + 4194304;          // partial 0 + final sum
  float* qn = (float*)(aO + 4194304);           // [bh*2048], prescaled
  float* kn = qn + 65536;

  unsigned short* aO1 = qbf;
  unsigned short* aO2 = Vh;

  prep_kernel  <<<dim3(3072), 256, 0, stream>>>(q, qbf, Wq, Wk, Wv, Wo, Wt);
  gemm_proj    <<<dim3(32,24), 512, 0, stream>>>(qbf, Wt, Qh, Vt, qn, kn, gm);
  attn_kernel  <<<dim3(1024), 256, 0, stream>>>(Qh, Kh, Vt, qn, kn, gm, aO, aO1, aO2);
  sum3_kernel  <<<dim3(2048), 256, 0, stream>>>(aO, aO1, aO2);
  gemm_out     <<<dim3(32,16), 512, 0, stream>>>(aO, Wt + 3*1048576, out);
}